// Round 1
// baseline (340.353 us; speedup 1.0000x reference)
//
#include <hip/hip_runtime.h>
#include <hip/hip_bf16.h>

// Bahdanau additive attention, B=32, L=2048, H=1024, fp32 in/out.
// Pipeline: prep_ua (Ua fp32 -> bf16 pre-fragmented) ; prep_q (q = query@Wa^T + Wa_b + Ua_b) ;
// score_kernel (fused k-proj MFMA + tanh + va-dot + mask) ; softmax ; context (attn@value) ; reduce.

#define B_ 32
#define L_ 2048
#define H_ 1024

typedef __attribute__((ext_vector_type(8))) short bf16x8;   // 8 bf16 in 4 VGPRs
typedef __attribute__((ext_vector_type(16))) float f32x16;  // 32x32 MFMA acc

__device__ inline unsigned pk_bf16(float a, float b) {
    unsigned r;
    asm("v_cvt_pk_bf16_f32 %0, %1, %2" : "=v"(r) : "v"(a), "v"(b));
    return r;  // low16 = bf16(a), high16 = bf16(b), RNE
}

__device__ inline float fast_tanh(float x) {
    // tanh(x) = 1 - 2/(1+e^{2x}); exact at +-inf, ~1e-6 err. 2 trans + 3 VALU.
    float e = __expf(2.f * x);
    return 1.f - 2.f * __builtin_amdgcn_rcpf(e + 1.f);
}

// ---- kernel 0a: Ua_w [1024][1024] fp32 -> bf16 pre-fragmented [s 0..63][nb 0..31][lane 0..63][j 0..7]
// B-frag of mfma_f32_32x32x16_bf16: lane l holds B[k=(l>>5)*8+j][col=l&31]; col = nb*32+(l&31), h = s*16+k.
__global__ void prep_ua(const float* __restrict__ Ua, ushort* __restrict__ Ufrag) {
    int t = blockIdx.x * 256 + threadIdx.x;   // 131072 slots of 8 elements
    int lane = t & 63;
    int nb   = (t >> 6) & 31;
    int s    = t >> 11;
    int o = nb * 32 + (lane & 31);
    int h = s * 16 + (lane >> 5) * 8;
    const float* src = Ua + o * H_ + h;
    float4 f0 = *(const float4*)(src);
    float4 f1 = *(const float4*)(src + 4);
    uint4 pk;
    pk.x = pk_bf16(f0.x, f0.y);
    pk.y = pk_bf16(f0.z, f0.w);
    pk.z = pk_bf16(f1.x, f1.y);
    pk.w = pk_bf16(f1.z, f1.w);
    *(uint4*)(Ufrag + (size_t)t * 8) = pk;
}

// ---- kernel 0b: qbuf[b][o] = sum_h query[b][h]*Wa_w[o][h] + Wa_b[o] + Ua_b[o]  (one wave per (b,o))
__global__ void prep_q(const float* __restrict__ query, const float* __restrict__ Wa_w,
                       const float* __restrict__ Wa_b, const float* __restrict__ Ua_b,
                       float* __restrict__ qbuf) {
    int wid  = blockIdx.x * 4 + (threadIdx.x >> 6);  // 32768 waves
    int lane = threadIdx.x & 63;
    int b = wid >> 10, o = wid & 1023;
    const float* qrow = query + b * H_;
    const float* wrow = Wa_w + o * H_;
    float acc = 0.f;
    #pragma unroll
    for (int i = 0; i < 16; ++i) {
        int h = i * 64 + lane;
        acc += qrow[h] * wrow[h];
    }
    #pragma unroll
    for (int m = 1; m < 64; m <<= 1) acc += __shfl_xor(acc, m);
    if (lane == 0) qbuf[b * H_ + o] = acc + Wa_b[o] + Ua_b[o];
}

// ---- kernel 1: fused k-projection GEMM + tanh + va-dot + mask -> scorebuf [B][L]
// Block: 64 l-rows (LDS-resident bf16 key tile, pre-fragmented) x all 1024 o in 2 passes.
// 8 waves; wave tile 64l x 64o = 2x2 frags of 32x32x16. No barriers in the K loop.
__launch_bounds__(512, 2)
__global__ void score_kernel(const float* __restrict__ key, const ushort* __restrict__ Ufrag,
                             const float* __restrict__ qbuf, const float* __restrict__ va_w,
                             const float* __restrict__ va_b, const int* __restrict__ mask,
                             float* __restrict__ scorebuf) {
    // A-frag layout: [mblk 0..1][s 0..63][lane 0..63][j 0..7], lane l holds A[row=l&31][k=(l>>5)*8+j]
    __shared__ ushort Alds[2 * 64 * 64 * 8];   // 128 KB
    __shared__ float s_part[8][64];

    int bid = blockIdx.x;              // 1024 = 32 b * 32 l-tiles
    int b = bid >> 5, lt = bid & 31;
    int l0 = lt * 64;
    int tid = threadIdx.x;
    int w = tid >> 6, lane = tid & 63;

    // ---- stage key tile: 64 rows x 1024 h fp32 -> bf16 fragments in LDS
    {
        int r  = tid >> 3;             // 0..63
        int c8 = (tid & 7) * 8;
        const float* krow = key + ((size_t)b * L_ + (l0 + r)) * H_;
        int mblk  = r >> 5;
        int lf_lo = r & 31;
        #pragma unroll
        for (int i = 0; i < 16; ++i) {
            int h = c8 + i * 64;
            float4 f0 = *(const float4*)(krow + h);
            float4 f1 = *(const float4*)(krow + h + 4);
            int s  = h >> 4;
            int lf = ((h >> 3) & 1) * 32 + lf_lo;
            uint4 pk;
            pk.x = pk_bf16(f0.x, f0.y);
            pk.y = pk_bf16(f0.z, f0.w);
            pk.z = pk_bf16(f1.x, f1.y);
            pk.w = pk_bf16(f1.z, f1.w);
            *(uint4*)&Alds[((mblk * 64 + s) * 64 + lf) * 8] = pk;
        }
    }
    __syncthreads();

    float vab = va_b[0];

    for (int p = 0; p < 2; ++p) {
        f32x16 acc[2][2] = {};                 // zero-init accumulators
        int nb0 = p * 16 + w * 2;              // wave's first 32-col block this pass
        #pragma unroll 4
        for (int s = 0; s < 64; ++s) {
            bf16x8 a0 = *(const bf16x8*)&Alds[((0 * 64 + s) * 64 + lane) * 8];
            bf16x8 a1 = *(const bf16x8*)&Alds[((1 * 64 + s) * 64 + lane) * 8];
            bf16x8 b0 = *(const bf16x8*)&Ufrag[(((size_t)s * 32 + nb0) * 64 + lane) * 8];
            bf16x8 b1 = *(const bf16x8*)&Ufrag[(((size_t)s * 32 + nb0 + 1) * 64 + lane) * 8];
            acc[0][0] = __builtin_amdgcn_mfma_f32_32x32x16_bf16(a0, b0, acc[0][0], 0, 0, 0);
            acc[1][0] = __builtin_amdgcn_mfma_f32_32x32x16_bf16(a1, b0, acc[1][0], 0, 0, 0);
            acc[0][1] = __builtin_amdgcn_mfma_f32_32x32x16_bf16(a0, b1, acc[0][1], 0, 0, 0);
            acc[1][1] = __builtin_amdgcn_mfma_f32_32x32x16_bf16(a1, b1, acc[1][1], 0, 0, 0);
        }
        // ---- epilogue: rowsum += va[col]*tanh(q[col] + C) ; C/D: col=lane&31, row=(r&3)+8*(r>>2)+4*(lane>>5)
        #pragma unroll
        for (int mi = 0; mi < 2; ++mi) {
            float rowsum[16];
            #pragma unroll
            for (int r = 0; r < 16; ++r) rowsum[r] = 0.f;
            #pragma unroll
            for (int ni = 0; ni < 2; ++ni) {
                int col = p * 512 + w * 64 + ni * 32 + (lane & 31);
                float qv  = qbuf[b * H_ + col];
                float vav = va_w[col];
                #pragma unroll
                for (int r = 0; r < 16; ++r) {
                    float t = fast_tanh(qv + acc[mi][ni][r]);
                    rowsum[r] += vav * t;
                }
            }
            #pragma unroll
            for (int r = 0; r < 16; ++r) {
                float v = rowsum[r];
                v += __shfl_xor(v, 1);  v += __shfl_xor(v, 2);  v += __shfl_xor(v, 4);
                v += __shfl_xor(v, 8);  v += __shfl_xor(v, 16);
                if ((lane & 31) == 0) {
                    int row = mi * 32 + (r & 3) + 8 * (r >> 2) + 4 * (lane >> 5);
                    if (p == 0) s_part[w][row] = v;
                    else        s_part[w][row] += v;
                }
            }
        }
    }
    __syncthreads();
    if (tid < 64) {
        float s = 0.f;
        #pragma unroll
        for (int ww = 0; ww < 8; ++ww) s += s_part[ww][tid];
        int l = l0 + tid;
        int m = mask[b * L_ + l];
        scorebuf[b * L_ + l] = (m == 0) ? -1e10f : (s + vab);
    }
}

// ---- kernel 2: masked softmax over L per batch -> attn [B][L]
__global__ void softmax_kernel(const float* __restrict__ scorebuf, float* __restrict__ attn) {
    __shared__ float red[16];
    int b = blockIdx.x;
    int tid = threadIdx.x;    // 256
    float v[8];
    float mx = -3e38f;
    #pragma unroll
    for (int i = 0; i < 8; ++i) {
        v[i] = scorebuf[b * L_ + tid + i * 256];
        mx = fmaxf(mx, v[i]);
    }
    #pragma unroll
    for (int m = 1; m < 64; m <<= 1) mx = fmaxf(mx, __shfl_xor(mx, m));
    if ((tid & 63) == 0) red[tid >> 6] = mx;
    __syncthreads();
    mx = fmaxf(fmaxf(red[0], red[1]), fmaxf(red[2], red[3]));
    float sum = 0.f;
    #pragma unroll
    for (int i = 0; i < 8; ++i) { v[i] = __expf(v[i] - mx); sum += v[i]; }
    #pragma unroll
    for (int m = 1; m < 64; m <<= 1) sum += __shfl_xor(sum, m);
    if ((tid & 63) == 0) red[8 + (tid >> 6)] = sum;
    __syncthreads();
    sum = red[8] + red[9] + red[10] + red[11];
    float inv = 1.f / sum;
    #pragma unroll
    for (int i = 0; i < 8; ++i) attn[b * L_ + tid + i * 256] = v[i] * inv;
}

// ---- kernel 3: partial context over 128-l chunks -> partial[b*16+ch][1024]
__global__ void context_kernel(const float* __restrict__ attn, const float* __restrict__ value,
                               float* __restrict__ partial) {
    int bid = blockIdx.x;            // 512 = 32 b * 16 chunks
    int b = bid >> 4, ch = bid & 15;
    int l0 = ch * 128;
    int tid = threadIdx.x;           // 256
    float4 acc = {0.f, 0.f, 0.f, 0.f};
    const float* vbase = value + ((size_t)b * L_ + l0) * H_ + tid * 4;
    const float* arow  = attn + b * L_ + l0;
    for (int l = 0; l < 128; ++l) {
        float a = arow[l];
        float4 vv = *(const float4*)(vbase + (size_t)l * H_);
        acc.x += a * vv.x; acc.y += a * vv.y; acc.z += a * vv.z; acc.w += a * vv.w;
    }
    *(float4*)(partial + (size_t)bid * H_ + tid * 4) = acc;
}

// ---- kernel 4: reduce 16 partials -> out [B][1][H]
__global__ void reduce_kernel(const float* __restrict__ partial, float* __restrict__ out) {
    int t = blockIdx.x * 256 + threadIdx.x;   // 32768
    int b = t >> 10, h = t & 1023;
    float s = 0.f;
    #pragma unroll
    for (int c = 0; c < 16; ++c) s += partial[(size_t)(b * 16 + c) * H_ + h];
    out[t] = s;
}

extern "C" void kernel_launch(void* const* d_in, const int* in_sizes, int n_in,
                              void* d_out, int out_size, void* d_ws, size_t ws_size,
                              hipStream_t stream) {
    const float* query = (const float*)d_in[0];
    const float* key   = (const float*)d_in[1];
    const float* value = (const float*)d_in[2];
    const int*   mask  = (const int*)d_in[3];
    const float* Wa_w  = (const float*)d_in[4];
    const float* Wa_b  = (const float*)d_in[5];
    const float* Ua_w  = (const float*)d_in[6];
    const float* Ua_b  = (const float*)d_in[7];
    const float* va_w  = (const float*)d_in[8];
    const float* va_b  = (const float*)d_in[9];
    float* out = (float*)d_out;

    char* ws = (char*)d_ws;
    ushort* Ufrag    = (ushort*)ws;                                   // 2 MB
    float*  qbuf     = (float*)(ws + (2u << 20));                     // 128 KB
    float*  scorebuf = (float*)(ws + (2u << 20) + (128u << 10));      // 256 KB
    float*  attnb    = (float*)(ws + (2u << 20) + (384u << 10));      // 256 KB
    float*  partial  = (float*)(ws + (2u << 20) + (640u << 10));      // 2 MB

    hipLaunchKernelGGL(prep_ua,        dim3(512),  dim3(256), 0, stream, Ua_w, Ufrag);
    hipLaunchKernelGGL(prep_q,         dim3(8192), dim3(256), 0, stream, query, Wa_w, Wa_b, Ua_b, qbuf);
    hipLaunchKernelGGL(score_kernel,   dim3(1024), dim3(512), 0, stream, key, Ufrag, qbuf, va_w, va_b, mask, scorebuf);
    hipLaunchKernelGGL(softmax_kernel, dim3(32),   dim3(256), 0, stream, scorebuf, attnb);
    hipLaunchKernelGGL(context_kernel, dim3(512),  dim3(256), 0, stream, attnb, value, partial);
    hipLaunchKernelGGL(reduce_kernel,  dim3(128),  dim3(256), 0, stream, partial, out);
}

// Round 2
// 306.772 us; speedup vs baseline: 1.1095x; 1.1095x over previous
//
#include <hip/hip_runtime.h>
#include <hip/hip_bf16.h>

// Bahdanau additive attention, B=32, L=2048, H=1024, fp32 in/out.
// prep_ua (Ua -> bf16 B-fragments) ; prep_q ; score_kernel (K-chunked double-buffered
// fused k-proj MFMA + tanh + va-dot + mask) ; softmax ; context ; reduce.

#define B_ 32
#define L_ 2048
#define H_ 1024

typedef __attribute__((ext_vector_type(8))) short bf16x8;   // 8 bf16 = 4 VGPRs
typedef __attribute__((ext_vector_type(16))) float f32x16;  // 32x32 MFMA acc

__device__ inline unsigned pk_bf16(float a, float b) {
    unsigned r;
    asm("v_cvt_pk_bf16_f32 %0, %1, %2" : "=v"(r) : "v"(a), "v"(b));
    return r;  // low16 = bf16(a), high16 = bf16(b), RNE
}

__device__ inline float fast_tanh(float x) {
    float e = __expf(2.f * x);
    return 1.f - 2.f * __builtin_amdgcn_rcpf(e + 1.f);
}

// Swizzled A-fragment slot: ushort index of frag (s-step, mblk, frag-lane lf).
// XOR of (s&3)<<1 into lane bits spreads staging writes across bank groups (<=2-way).
__device__ inline int aslot(int s, int m, int lf) {
    return (((s * 2 + m) * 64) + (lf ^ ((s & 3) << 1))) * 8;
}

// ---- kernel 0a: Ua_w [1024][1024] fp32 -> bf16 B-fragments [s 0..63][nb 0..31][lane][j 0..7]
// B-frag of mfma_f32_32x32x16_bf16: lane l holds B[k=(l>>5)*8+j][col=nb*32+(l&31)], h = s*16+k.
__global__ void prep_ua(const float* __restrict__ Ua, ushort* __restrict__ Ufrag) {
    int t = blockIdx.x * 256 + threadIdx.x;   // 131072 slots of 8 elements
    int lane = t & 63;
    int nb   = (t >> 6) & 31;
    int s    = t >> 11;
    int o = nb * 32 + (lane & 31);
    int h = s * 16 + (lane >> 5) * 8;
    const float* src = Ua + o * H_ + h;
    float4 f0 = *(const float4*)(src);
    float4 f1 = *(const float4*)(src + 4);
    uint4 pk;
    pk.x = pk_bf16(f0.x, f0.y);
    pk.y = pk_bf16(f0.z, f0.w);
    pk.z = pk_bf16(f1.x, f1.y);
    pk.w = pk_bf16(f1.z, f1.w);
    *(uint4*)(Ufrag + (size_t)t * 8) = pk;
}

// ---- kernel 0b: qbuf[b][o] = query[b]·Wa_w[o] + Wa_b[o] + Ua_b[o]
__global__ void prep_q(const float* __restrict__ query, const float* __restrict__ Wa_w,
                       const float* __restrict__ Wa_b, const float* __restrict__ Ua_b,
                       float* __restrict__ qbuf) {
    int wid  = blockIdx.x * 4 + (threadIdx.x >> 6);  // 32768 waves
    int lane = threadIdx.x & 63;
    int b = wid >> 10, o = wid & 1023;
    const float* qrow = query + b * H_;
    const float* wrow = Wa_w + o * H_;
    float acc = 0.f;
    #pragma unroll
    for (int i = 0; i < 16; ++i) {
        int h = i * 64 + lane;
        acc += qrow[h] * wrow[h];
    }
    #pragma unroll
    for (int m = 1; m < 64; m <<= 1) acc += __shfl_xor(acc, m);
    if (lane == 0) qbuf[b * H_ + o] = acc + Wa_b[o] + Ua_b[o];
}

// ---- kernel 1: fused k-projection GEMM + tanh + va-dot + mask -> scorebuf [B][L]
// Block: 64 l-rows x ALL 1024 o (8 waves x 128 o each, acc[2][4] f32x16 = 128 VGPR).
// K chunked at 256 (4 chunks), A-chunk double-buffered in LDS (2 x 32 KB).
// Staging loads for chunk c+1 issued BEFORE compute of chunk c (latency hidden under MFMA);
// bf16 convert + swizzled ds_write after compute; one barrier per chunk.
__launch_bounds__(512, 2)
__global__ void score_kernel(const float* __restrict__ key, const ushort* __restrict__ Ufrag,
                             const float* __restrict__ qbuf, const float* __restrict__ va_w,
                             const float* __restrict__ va_b, const int* __restrict__ mask,
                             float* __restrict__ scorebuf) {
    __shared__ ushort Alds[2][16 * 2 * 64 * 8];   // 2 x 32 KB
    __shared__ float s_part[8][64];

    int bid = blockIdx.x;              // 1024 = 32 b * 32 l-tiles
    int b = bid >> 5, lt = bid & 31;
    int l0 = lt * 64;
    int tid = threadIdx.x;
    int w = tid >> 6, lane = tid & 63;

    // staging coords for this thread (same every chunk)
    int r    = tid >> 3;               // 0..63 row within tile
    int mblk = r >> 5;
    int rr   = r & 31;
    int c0   = (tid & 7) * 8;          // 0..56, 8-float column start
    const float* krow = key + ((size_t)b * L_ + (l0 + r)) * H_;

    // ---- prologue: stage chunk 0
    {
        #pragma unroll
        for (int i = 0; i < 4; ++i) {
            int col = c0 + i * 64;                 // 0..255 within chunk
            float4 f0 = *(const float4*)(krow + col);
            float4 f1 = *(const float4*)(krow + col + 4);
            int s  = col >> 4;
            int p  = (col >> 3) & 1;
            int lf = p * 32 + rr;
            uint4 pk;
            pk.x = pk_bf16(f0.x, f0.y);
            pk.y = pk_bf16(f0.z, f0.w);
            pk.z = pk_bf16(f1.x, f1.y);
            pk.w = pk_bf16(f1.z, f1.w);
            *(uint4*)&Alds[0][aslot(s, mblk, lf)] = pk;
        }
    }
    __syncthreads();

    int nb0 = w * 4;                               // wave's 4 o-blocks (128 cols)
    const ushort* Uw = Ufrag + ((size_t)nb0 * 64 + lane) * 8;

    f32x16 acc[2][4] = {};
    bf16x8 bc[4];
    #pragma unroll
    for (int ni = 0; ni < 4; ++ni)
        bc[ni] = *(const bf16x8*)(Uw + ni * 512);  // B(s=0)

    for (int kc = 0; kc < 4; ++kc) {
        int cur = kc & 1;
        // issue staging loads for chunk kc+1 (consumed after the 16 MFMA steps)
        float4 ld[4][2];
        if (kc < 3) {
            #pragma unroll
            for (int i = 0; i < 4; ++i) {
                int col = (kc + 1) * 256 + c0 + i * 64;
                ld[i][0] = *(const float4*)(krow + col);
                ld[i][1] = *(const float4*)(krow + col + 4);
            }
        }
        #pragma unroll
        for (int s = 0; s < 16; ++s) {
            bf16x8 a0 = *(const bf16x8*)&Alds[cur][aslot(s, 0, lane)];
            bf16x8 a1 = *(const bf16x8*)&Alds[cur][aslot(s, 1, lane)];
            int sn = (kc * 16 + s + 1) & 63;       // next B step (wraps harmlessly)
            bf16x8 bn[4];
            #pragma unroll
            for (int ni = 0; ni < 4; ++ni)
                bn[ni] = *(const bf16x8*)(Uw + (size_t)sn * 16384 + ni * 512);
            #pragma unroll
            for (int ni = 0; ni < 4; ++ni) {
                acc[0][ni] = __builtin_amdgcn_mfma_f32_32x32x16_bf16(a0, bc[ni], acc[0][ni], 0, 0, 0);
                acc[1][ni] = __builtin_amdgcn_mfma_f32_32x32x16_bf16(a1, bc[ni], acc[1][ni], 0, 0, 0);
            }
            #pragma unroll
            for (int ni = 0; ni < 4; ++ni) bc[ni] = bn[ni];
        }
        if (kc < 3) {
            int nxt = cur ^ 1;
            #pragma unroll
            for (int i = 0; i < 4; ++i) {
                int col = c0 + i * 64;
                int s  = col >> 4;
                int p  = (col >> 3) & 1;
                int lf = p * 32 + rr;
                uint4 pk;
                pk.x = pk_bf16(ld[i][0].x, ld[i][0].y);
                pk.y = pk_bf16(ld[i][0].z, ld[i][0].w);
                pk.z = pk_bf16(ld[i][1].x, ld[i][1].y);
                pk.w = pk_bf16(ld[i][1].z, ld[i][1].w);
                *(uint4*)&Alds[nxt][aslot(s, mblk, lf)] = pk;
            }
            __syncthreads();
        }
    }

    // ---- epilogue: rowsum = sum_o va[o]*tanh(q[o] + acc) ; C/D: col=lane&31, row=(r&3)+8*(r>>2)+4*(lane>>5)
    float vab = va_b[0];
    #pragma unroll
    for (int mi = 0; mi < 2; ++mi) {
        float rowsum[16];
        #pragma unroll
        for (int rg = 0; rg < 16; ++rg) rowsum[rg] = 0.f;
        #pragma unroll
        for (int ni = 0; ni < 4; ++ni) {
            int col = w * 128 + ni * 32 + (lane & 31);
            float qv  = qbuf[b * H_ + col];
            float vav = va_w[col];
            #pragma unroll
            for (int rg = 0; rg < 16; ++rg)
                rowsum[rg] += vav * fast_tanh(qv + acc[mi][ni][rg]);
        }
        #pragma unroll
        for (int rg = 0; rg < 16; ++rg) {
            float v = rowsum[rg];
            v += __shfl_xor(v, 1);  v += __shfl_xor(v, 2);  v += __shfl_xor(v, 4);
            v += __shfl_xor(v, 8);  v += __shfl_xor(v, 16);
            if ((lane & 31) == 0) {
                int row = mi * 32 + (rg & 3) + 8 * (rg >> 2) + 4 * (lane >> 5);
                s_part[w][row] = v;
            }
        }
    }
    __syncthreads();
    if (tid < 64) {
        float s = 0.f;
        #pragma unroll
        for (int ww = 0; ww < 8; ++ww) s += s_part[ww][tid];
        int l = l0 + tid;
        int m = mask[b * L_ + l];
        scorebuf[b * L_ + l] = (m == 0) ? -1e10f : (s + vab);
    }
}

// ---- kernel 2: masked softmax over L per batch -> attn [B][L]
__global__ void softmax_kernel(const float* __restrict__ scorebuf, float* __restrict__ attn) {
    __shared__ float red[16];
    int b = blockIdx.x;
    int tid = threadIdx.x;    // 256
    float v[8];
    float mx = -3e38f;
    #pragma unroll
    for (int i = 0; i < 8; ++i) {
        v[i] = scorebuf[b * L_ + tid + i * 256];
        mx = fmaxf(mx, v[i]);
    }
    #pragma unroll
    for (int m = 1; m < 64; m <<= 1) mx = fmaxf(mx, __shfl_xor(mx, m));
    if ((tid & 63) == 0) red[tid >> 6] = mx;
    __syncthreads();
    mx = fmaxf(fmaxf(red[0], red[1]), fmaxf(red[2], red[3]));
    float sum = 0.f;
    #pragma unroll
    for (int i = 0; i < 8; ++i) { v[i] = __expf(v[i] - mx); sum += v[i]; }
    #pragma unroll
    for (int m = 1; m < 64; m <<= 1) sum += __shfl_xor(sum, m);
    if ((tid & 63) == 0) red[8 + (tid >> 6)] = sum;
    __syncthreads();
    sum = red[8] + red[9] + red[10] + red[11];
    float inv = 1.f / sum;
    #pragma unroll
    for (int i = 0; i < 8; ++i) attn[b * L_ + tid + i * 256] = v[i] * inv;
}

// ---- kernel 3: partial context over 128-l chunks -> partial[b*16+ch][1024]
__global__ void context_kernel(const float* __restrict__ attn, const float* __restrict__ value,
                               float* __restrict__ partial) {
    int bid = blockIdx.x;            // 512 = 32 b * 16 chunks
    int b = bid >> 4, ch = bid & 15;
    int l0 = ch * 128;
    int tid = threadIdx.x;           // 256
    float4 acc = {0.f, 0.f, 0.f, 0.f};
    const float* vbase = value + ((size_t)b * L_ + l0) * H_ + tid * 4;
    const float* arow  = attn + b * L_ + l0;
    for (int l = 0; l < 128; ++l) {
        float a = arow[l];
        float4 vv = *(const float4*)(vbase + (size_t)l * H_);
        acc.x += a * vv.x; acc.y += a * vv.y; acc.z += a * vv.z; acc.w += a * vv.w;
    }
    *(float4*)(partial + (size_t)bid * H_ + tid * 4) = acc;
}

// ---- kernel 4: reduce 16 partials -> out [B][1][H]
__global__ void reduce_kernel(const float* __restrict__ partial, float* __restrict__ out) {
    int t = blockIdx.x * 256 + threadIdx.x;   // 32768
    int b = t >> 10, h = t & 1023;
    float s = 0.f;
    #pragma unroll
    for (int c = 0; c < 16; ++c) s += partial[(size_t)(b * 16 + c) * H_ + h];
    out[t] = s;
}

extern "C" void kernel_launch(void* const* d_in, const int* in_sizes, int n_in,
                              void* d_out, int out_size, void* d_ws, size_t ws_size,
                              hipStream_t stream) {
    const float* query = (const float*)d_in[0];
    const float* key   = (const float*)d_in[1];
    const float* value = (const float*)d_in[2];
    const int*   mask  = (const int*)d_in[3];
    const float* Wa_w  = (const float*)d_in[4];
    const float* Wa_b  = (const float*)d_in[5];
    const float* Ua_w  = (const float*)d_in[6];
    const float* Ua_b  = (const float*)d_in[7];
    const float* va_w  = (const float*)d_in[8];
    const float* va_b  = (const float*)d_in[9];
    float* out = (float*)d_out;

    char* ws = (char*)d_ws;
    ushort* Ufrag    = (ushort*)ws;                                   // 2 MB
    float*  qbuf     = (float*)(ws + (2u << 20));                     // 128 KB
    float*  scorebuf = (float*)(ws + (2u << 20) + (128u << 10));      // 256 KB
    float*  attnb    = (float*)(ws + (2u << 20) + (384u << 10));      // 256 KB
    float*  partial  = (float*)(ws + (2u << 20) + (640u << 10));      // 2 MB

    hipLaunchKernelGGL(prep_ua,        dim3(512),  dim3(256), 0, stream, Ua_w, Ufrag);
    hipLaunchKernelGGL(prep_q,         dim3(8192), dim3(256), 0, stream, query, Wa_w, Wa_b, Ua_b, qbuf);
    hipLaunchKernelGGL(score_kernel,   dim3(1024), dim3(512), 0, stream, key, Ufrag, qbuf, va_w, va_b, mask, scorebuf);
    hipLaunchKernelGGL(softmax_kernel, dim3(32),   dim3(256), 0, stream, scorebuf, attnb);
    hipLaunchKernelGGL(context_kernel, dim3(512),  dim3(256), 0, stream, attnb, value, partial);
    hipLaunchKernelGGL(reduce_kernel,  dim3(128),  dim3(256), 0, stream, partial, out);
}

// Round 4
// 252.927 us; speedup vs baseline: 1.3457x; 1.2129x over previous
//
#include <hip/hip_runtime.h>
#include <hip/hip_bf16.h>

// Bahdanau additive attention, B=32, L=2048, H=1024, fp32 in/out.
// prep_ua (Ua -> bf16 B-fragments) ; prep_q ; score_kernel (K-chunked double-buffered
// fused k-proj MFMA + tanh + va-dot + mask, depth-2 B prefetch, nt key loads) ;
// softmax ; context ; reduce.

#define B_ 32
#define L_ 2048
#define H_ 1024

typedef __attribute__((ext_vector_type(8))) short bf16x8;   // 8 bf16 = 4 VGPRs
typedef __attribute__((ext_vector_type(16))) float f32x16;  // 32x32 MFMA acc
typedef __attribute__((ext_vector_type(4))) float f32x4;    // native float4 for nt loads

__device__ inline unsigned pk_bf16(float a, float b) {
    unsigned r;
    asm("v_cvt_pk_bf16_f32 %0, %1, %2" : "=v"(r) : "v"(a), "v"(b));
    return r;  // low16 = bf16(a), high16 = bf16(b), RNE
}

__device__ inline float fast_tanh(float x) {
    float e = __expf(2.f * x);
    return 1.f - 2.f * __builtin_amdgcn_rcpf(e + 1.f);
}

__device__ inline f32x4 ntload4(const float* p) {
    // streaming load: evict-first so Ufrag stays L2-resident
    return __builtin_nontemporal_load((const f32x4*)p);
}

// Swizzled A-fragment slot: ushort index of frag (s-step, mblk, frag-lane lf).
__device__ inline int aslot(int s, int m, int lf) {
    return (((s * 2 + m) * 64) + (lf ^ ((s & 3) << 1))) * 8;
}

// ---- kernel 0a: Ua_w [1024][1024] fp32 -> bf16 B-fragments [s 0..63][nb 0..31][lane][j 0..7]
__global__ void prep_ua(const float* __restrict__ Ua, ushort* __restrict__ Ufrag) {
    int t = blockIdx.x * 256 + threadIdx.x;   // 131072 slots of 8 elements
    int lane = t & 63;
    int nb   = (t >> 6) & 31;
    int s    = t >> 11;
    int o = nb * 32 + (lane & 31);
    int h = s * 16 + (lane >> 5) * 8;
    const float* src = Ua + o * H_ + h;
    f32x4 f0 = *(const f32x4*)(src);
    f32x4 f1 = *(const f32x4*)(src + 4);
    uint4 pk;
    pk.x = pk_bf16(f0.x, f0.y);
    pk.y = pk_bf16(f0.z, f0.w);
    pk.z = pk_bf16(f1.x, f1.y);
    pk.w = pk_bf16(f1.z, f1.w);
    *(uint4*)(Ufrag + (size_t)t * 8) = pk;
}

// ---- kernel 0b: qbuf[b][o] = query[b]·Wa_w[o] + Wa_b[o] + Ua_b[o]
__global__ void prep_q(const float* __restrict__ query, const float* __restrict__ Wa_w,
                       const float* __restrict__ Wa_b, const float* __restrict__ Ua_b,
                       float* __restrict__ qbuf) {
    int wid  = blockIdx.x * 4 + (threadIdx.x >> 6);  // 32768 waves
    int lane = threadIdx.x & 63;
    int b = wid >> 10, o = wid & 1023;
    const float* qrow = query + b * H_;
    const float* wrow = Wa_w + o * H_;
    float acc = 0.f;
    #pragma unroll
    for (int i = 0; i < 16; ++i) {
        int h = i * 64 + lane;
        acc += qrow[h] * wrow[h];
    }
    #pragma unroll
    for (int m = 1; m < 64; m <<= 1) acc += __shfl_xor(acc, m);
    if (lane == 0) qbuf[b * H_ + o] = acc + Wa_b[o] + Ua_b[o];
}

// ---- kernel 1: fused k-projection GEMM + tanh + va-dot + mask -> scorebuf [B][L]
// 64 l-rows x all 1024 o; 8 waves x (64l x 128o), acc[2][4] f32x16 (128 AGPR).
// K chunked at 256, LDS double-buffered; B-fragment prefetch depth 2 (bc/b1/bn rotation).
__launch_bounds__(512, 2)
__global__ void score_kernel(const float* __restrict__ key, const ushort* __restrict__ Ufrag,
                             const float* __restrict__ qbuf, const float* __restrict__ va_w,
                             const float* __restrict__ va_b, const int* __restrict__ mask,
                             float* __restrict__ scorebuf) {
    __shared__ ushort Alds[2][16 * 2 * 64 * 8];   // 2 x 32 KB
    __shared__ float s_part[8][64];

    int bid = blockIdx.x;              // 1024 = 32 b * 32 l-tiles
    int b = bid >> 5, lt = bid & 31;
    int l0 = lt * 64;
    int tid = threadIdx.x;
    int w = tid >> 6, lane = tid & 63;

    // staging coords (fixed per thread)
    int r    = tid >> 3;               // 0..63
    int mblk = r >> 5;
    int rr   = r & 31;
    int c0   = (tid & 7) * 8;          // 0..56
    const float* krow = key + ((size_t)b * L_ + (l0 + r)) * H_;

    // ---- prologue: stage chunk 0 (nt loads: streaming)
    {
        #pragma unroll
        for (int i = 0; i < 4; ++i) {
            int col = c0 + i * 64;
            f32x4 f0 = ntload4(krow + col);
            f32x4 f1 = ntload4(krow + col + 4);
            int s  = col >> 4;
            int p  = (col >> 3) & 1;
            int lf = p * 32 + rr;
            uint4 pk;
            pk.x = pk_bf16(f0.x, f0.y);
            pk.y = pk_bf16(f0.z, f0.w);
            pk.z = pk_bf16(f1.x, f1.y);
            pk.w = pk_bf16(f1.z, f1.w);
            *(uint4*)&Alds[0][aslot(s, mblk, lf)] = pk;
        }
    }

    int nb0 = w * 4;                               // wave's 4 o-blocks (128 cols)
    const ushort* Uw = Ufrag + ((size_t)nb0 * 64 + lane) * 8;

    f32x16 acc[2][4] = {};
    bf16x8 bc[4], b1[4];
    #pragma unroll
    for (int ni = 0; ni < 4; ++ni) {
        bc[ni] = *(const bf16x8*)(Uw + ni * 512);                    // B(s=0)
        b1[ni] = *(const bf16x8*)(Uw + (size_t)16384 + ni * 512);    // B(s=1)
    }
    __syncthreads();

    for (int kc = 0; kc < 4; ++kc) {
        int cur = kc & 1;
        // staging loads for chunk kc+1, consumed after the 16 MFMA steps
        f32x4 ld[4][2];
        if (kc < 3) {
            #pragma unroll
            for (int i = 0; i < 4; ++i) {
                int col = (kc + 1) * 256 + c0 + i * 64;
                ld[i][0] = ntload4(krow + col);
                ld[i][1] = ntload4(krow + col + 4);
            }
        }
        #pragma unroll
        for (int s = 0; s < 16; ++s) {
            bf16x8 a0 = *(const bf16x8*)&Alds[cur][aslot(s, 0, lane)];
            bf16x8 a1 = *(const bf16x8*)&Alds[cur][aslot(s, 1, lane)];
            int sn = (kc * 16 + s + 2) & 63;       // depth-2 prefetch (wrap harmless)
            bf16x8 bn[4];
            #pragma unroll
            for (int ni = 0; ni < 4; ++ni)
                bn[ni] = *(const bf16x8*)(Uw + (size_t)sn * 16384 + ni * 512);
            #pragma unroll
            for (int ni = 0; ni < 4; ++ni) {
                acc[0][ni] = __builtin_amdgcn_mfma_f32_32x32x16_bf16(a0, bc[ni], acc[0][ni], 0, 0, 0);
                acc[1][ni] = __builtin_amdgcn_mfma_f32_32x32x16_bf16(a1, bc[ni], acc[1][ni], 0, 0, 0);
            }
            #pragma unroll
            for (int ni = 0; ni < 4; ++ni) { bc[ni] = b1[ni]; b1[ni] = bn[ni]; }
        }
        if (kc < 3) {
            int nxt = cur ^ 1;
            #pragma unroll
            for (int i = 0; i < 4; ++i) {
                int col = c0 + i * 64;
                int s  = col >> 4;
                int p  = (col >> 3) & 1;
                int lf = p * 32 + rr;
                uint4 pk;
                pk.x = pk_bf16(ld[i][0].x, ld[i][0].y);
                pk.y = pk_bf16(ld[i][0].z, ld[i][0].w);
                pk.z = pk_bf16(ld[i][1].x, ld[i][1].y);
                pk.w = pk_bf16(ld[i][1].z, ld[i][1].w);
                *(uint4*)&Alds[nxt][aslot(s, mblk, lf)] = pk;
            }
            __syncthreads();
        }
    }

    // ---- epilogue: rowsum = sum_o va[o]*tanh(q[o] + acc)
    float vab = va_b[0];
    #pragma unroll
    for (int mi = 0; mi < 2; ++mi) {
        float rowsum[16];
        #pragma unroll
        for (int rg = 0; rg < 16; ++rg) rowsum[rg] = 0.f;
        #pragma unroll
        for (int ni = 0; ni < 4; ++ni) {
            int col = w * 128 + ni * 32 + (lane & 31);
            float qv  = qbuf[b * H_ + col];
            float vav = va_w[col];
            #pragma unroll
            for (int rg = 0; rg < 16; ++rg)
                rowsum[rg] += vav * fast_tanh(qv + acc[mi][ni][rg]);
        }
        #pragma unroll
        for (int rg = 0; rg < 16; ++rg) {
            float v = rowsum[rg];
            v += __shfl_xor(v, 1);  v += __shfl_xor(v, 2);  v += __shfl_xor(v, 4);
            v += __shfl_xor(v, 8);  v += __shfl_xor(v, 16);
            if ((lane & 31) == 0) {
                int row = mi * 32 + (rg & 3) + 8 * (rg >> 2) + 4 * (lane >> 5);
                s_part[w][row] = v;
            }
        }
    }
    __syncthreads();
    if (tid < 64) {
        float s = 0.f;
        #pragma unroll
        for (int ww = 0; ww < 8; ++ww) s += s_part[ww][tid];
        int l = l0 + tid;
        int m = mask[b * L_ + l];
        scorebuf[b * L_ + l] = (m == 0) ? -1e10f : (s + vab);
    }
}

// ---- kernel 2: masked softmax over L per batch -> attn [B][L]
__global__ void softmax_kernel(const float* __restrict__ scorebuf, float* __restrict__ attn) {
    __shared__ float red[16];
    int b = blockIdx.x;
    int tid = threadIdx.x;    // 256
    float v[8];
    float mx = -3e38f;
    #pragma unroll
    for (int i = 0; i < 8; ++i) {
        v[i] = scorebuf[b * L_ + tid + i * 256];
        mx = fmaxf(mx, v[i]);
    }
    #pragma unroll
    for (int m = 1; m < 64; m <<= 1) mx = fmaxf(mx, __shfl_xor(mx, m));
    if ((tid & 63) == 0) red[tid >> 6] = mx;
    __syncthreads();
    mx = fmaxf(fmaxf(red[0], red[1]), fmaxf(red[2], red[3]));
    float sum = 0.f;
    #pragma unroll
    for (int i = 0; i < 8; ++i) { v[i] = __expf(v[i] - mx); sum += v[i]; }
    #pragma unroll
    for (int m = 1; m < 64; m <<= 1) sum += __shfl_xor(sum, m);
    if ((tid & 63) == 0) red[8 + (tid >> 6)] = sum;
    __syncthreads();
    sum = red[8] + red[9] + red[10] + red[11];
    float inv = 1.f / sum;
    #pragma unroll
    for (int i = 0; i < 8; ++i) attn[b * L_ + tid + i * 256] = v[i] * inv;
}

// ---- kernel 3: partial context over 128-l chunks -> partial[b*16+ch][1024]
__global__ void context_kernel(const float* __restrict__ attn, const float* __restrict__ value,
                               float* __restrict__ partial) {
    int bid = blockIdx.x;            // 512 = 32 b * 16 chunks
    int b = bid >> 4, ch = bid & 15;
    int l0 = ch * 128;
    int tid = threadIdx.x;           // 256
    f32x4 acc = {0.f, 0.f, 0.f, 0.f};
    const float* vbase = value + ((size_t)b * L_ + l0) * H_ + tid * 4;
    const float* arow  = attn + b * L_ + l0;
    for (int l = 0; l < 128; ++l) {
        float a = arow[l];
        f32x4 vv = *(const f32x4*)(vbase + (size_t)l * H_);
        acc.x += a * vv.x; acc.y += a * vv.y; acc.z += a * vv.z; acc.w += a * vv.w;
    }
    *(f32x4*)(partial + (size_t)bid * H_ + tid * 4) = acc;
}

// ---- kernel 4: reduce 16 partials -> out [B][1][H]
__global__ void reduce_kernel(const float* __restrict__ partial, float* __restrict__ out) {
    int t = blockIdx.x * 256 + threadIdx.x;   // 32768
    int b = t >> 10, h = t & 1023;
    float s = 0.f;
    #pragma unroll
    for (int c = 0; c < 16; ++c) s += partial[(size_t)(b * 16 + c) * H_ + h];
    out[t] = s;
}

extern "C" void kernel_launch(void* const* d_in, const int* in_sizes, int n_in,
                              void* d_out, int out_size, void* d_ws, size_t ws_size,
                              hipStream_t stream) {
    const float* query = (const float*)d_in[0];
    const float* key   = (const float*)d_in[1];
    const float* value = (const float*)d_in[2];
    const int*   mask  = (const int*)d_in[3];
    const float* Wa_w  = (const float*)d_in[4];
    const float* Wa_b  = (const float*)d_in[5];
    const float* Ua_w  = (const float*)d_in[6];
    const float* Ua_b  = (const float*)d_in[7];
    const float* va_w  = (const float*)d_in[8];
    const float* va_b  = (const float*)d_in[9];
    float* out = (float*)d_out;

    char* ws = (char*)d_ws;
    ushort* Ufrag    = (ushort*)ws;                                   // 2 MB
    float*  qbuf     = (float*)(ws + (2u << 20));                     // 128 KB
    float*  scorebuf = (float*)(ws + (2u << 20) + (128u << 10));      // 256 KB
    float*  attnb    = (float*)(ws + (2u << 20) + (384u << 10));      // 256 KB
    float*  partial  = (float*)(ws + (2u << 20) + (640u << 10));      // 2 MB

    hipLaunchKernelGGL(prep_ua,        dim3(512),  dim3(256), 0, stream, Ua_w, Ufrag);
    hipLaunchKernelGGL(prep_q,         dim3(8192), dim3(256), 0, stream, query, Wa_w, Wa_b, Ua_b, qbuf);
    hipLaunchKernelGGL(score_kernel,   dim3(1024), dim3(512), 0, stream, key, Ufrag, qbuf, va_w, va_b, mask, scorebuf);
    hipLaunchKernelGGL(softmax_kernel, dim3(32),   dim3(256), 0, stream, scorebuf, attnb);
    hipLaunchKernelGGL(context_kernel, dim3(512),  dim3(256), 0, stream, attnb, value, partial);
    hipLaunchKernelGGL(reduce_kernel,  dim3(128),  dim3(256), 0, stream, partial, out);
}